// Round 18
// baseline (239.631 us; speedup 1.0000x reference)
//
#include <hip/hip_runtime.h>
#include <math.h>

#define NFEAT 256
#define NHID 128
#define NCLASS 40
#define BNODES 128
#define BSHIFT 7
#define BCAP 2688
#define MAXBK 1024
#define EPB 16384

typedef unsigned short ushort_t;
typedef unsigned int uint_t;
typedef unsigned char uchar_t;
typedef __attribute__((ext_vector_type(8))) short bf16x8;
typedef __attribute__((ext_vector_type(4))) float f32x4;
typedef __attribute__((ext_vector_type(2))) float f32x2;

static __device__ inline float bf2f(ushort_t u) {
    union { uint_t u; float f; } v; v.u = (uint_t)u << 16; return v.f;
}
static __device__ inline float lo2f(uint_t u) {
    union { uint_t u; float f; } v; v.u = u << 16; return v.f;
}
static __device__ inline float hi2f(uint_t u) {
    union { uint_t u; float f; } v; v.u = u & 0xFFFF0000u; return v.f;
}
static __device__ inline ushort_t f2bf(float f) {
    uint_t u = __float_as_uint(f);
    u += 0x7FFF + ((u >> 16) & 1);           // round-to-nearest-even
    return (ushort_t)(u >> 16);
}
// fused bf16-extract + fp32 accumulate
static __device__ inline float dot2bf(uint_t pk, uint_t mask, float c) {
    float r;
    asm("v_dot2_f32_bf16 %0, %1, %2, %3" : "=v"(r) : "v"(pk), "v"(mask), "v"(c));
    return r;
}
#define LOMASK 0x00003F80u
#define HIMASK 0x3F800000u

// async global->LDS 16B (dest = wave-uniform base + lane*16)
static __device__ __forceinline__ void gload16(const void* g, void* l) {
    __builtin_amdgcn_global_load_lds(
        (const __attribute__((address_space(1))) uint_t*)g,
        (__attribute__((address_space(3))) uint_t*)l, 16, 0, 0);
}

// fp8 e4m3 pack/unpack (gfx950 native)
static __device__ inline ushort_t pk2fp8(float a, float b) {
    return (ushort_t)__builtin_amdgcn_cvt_pk_fp8_f32(a, b, 0, false);
}
static __device__ inline f32x2 unpk_lo(uint_t w) {
    return __builtin_amdgcn_cvt_pk_f32_fp8(w, false);
}
static __device__ inline f32x2 unpk_hi(uint_t w) {
    return __builtin_amdgcn_cvt_pk_f32_fp8(w, true);
}

// ---------------- edge partition by dst-bucket: hist / scan / scatter --------

__global__ __launch_bounds__(256) void k_ehist(const int* __restrict__ dst,
                                               int* __restrict__ cnt,
                                               int E, int nbk, int nblk) {
    __shared__ int hist[MAXBK];
    int tid = threadIdx.x, be = blockIdx.x;
    for (int i = tid; i < nbk; i += 256) hist[i] = 0;
    __syncthreads();
    int e0 = be * EPB, e1 = min(e0 + EPB, E);
    for (int e = e0 + tid; e < e1; e += 256)
        atomicAdd(&hist[dst[e] >> BSHIFT], 1);          // LDS int atomic: native
    __syncthreads();
    for (int i = tid; i < nbk; i += 256)
        cnt[(size_t)i * nblk + be] = hist[i];
}

__global__ __launch_bounds__(128) void k_escan(int* __restrict__ cnt,
                                               int* __restrict__ bcnt, int nblk) {
    __shared__ int buf[128];
    int b = blockIdx.x, tid = threadIdx.x;
    int v = (tid < nblk) ? cnt[(size_t)b * nblk + tid] : 0;
    buf[tid] = v;
    __syncthreads();
    for (int off = 1; off < 128; off <<= 1) {
        int t = (tid >= off) ? buf[tid - off] : 0;
        __syncthreads();
        buf[tid] += t;
        __syncthreads();
    }
    if (tid < nblk) cnt[(size_t)b * nblk + tid] = buf[tid] - v;   // exclusive
    if (tid == 127) bcnt[b] = buf[127];                           // total
}

__global__ __launch_bounds__(256) void k_escatter(const int* __restrict__ src,
                                                  const int* __restrict__ dst,
                                                  const int* __restrict__ cnt,
                                                  uint_t* __restrict__ bstore,
                                                  int E, int nbk, int nblk) {
    __shared__ int cur[MAXBK];
    int tid = threadIdx.x, be = blockIdx.x;
    for (int i = tid; i < nbk; i += 256)
        cur[i] = cnt[(size_t)i * nblk + be];
    __syncthreads();
    int e0 = be * EPB, e1 = min(e0 + EPB, E);
    for (int e = e0 + tid; e < e1; e += 256) {
        int d = dst[e];
        int b = d >> BSHIFT;
        int p = atomicAdd(&cur[b], 1);                  // LDS int atomic: native
        if (p < BCAP)
            bstore[(size_t)b * BCAP + p] = ((uint_t)(d & (BNODES - 1)) << 20) | (uint_t)src[e];
    }
}

// ---------------- per-bucket counting sort (LDS), + rp + dinv ----------------

__global__ __launch_bounds__(256) void k_bsort(const uint_t* __restrict__ bstore,
                                               const int* __restrict__ bcnt,
                                               uint_t* __restrict__ colsort,
                                               int* __restrict__ rp,
                                               float* __restrict__ dinv, int N) {
    __shared__ uint_t rec[BCAP];
    __shared__ uint_t srt[BCAP];
    __shared__ int hist[BNODES];
    __shared__ int scan[BNODES];
    __shared__ int cur[BNODES];
    int b = blockIdx.x, tid = threadIdx.x;
    if (tid < BNODES) hist[tid] = 0;
    __syncthreads();
    int cnt = min(bcnt[b], BCAP);
    const uint_t* gp = &bstore[(size_t)b * BCAP];
    for (int e = tid; e < cnt; e += 256) {
        uint_t r = gp[e];
        rec[e] = r;
        atomicAdd(&hist[r >> 20], 1);          // int LDS atomic: native
    }
    __syncthreads();
    if (tid < BNODES) scan[tid] = hist[tid];
    __syncthreads();
    for (int off = 1; off < BNODES; off <<= 1) {
        int v = 0;
        if (tid < BNODES && tid >= off) v = scan[tid - off];
        __syncthreads();
        if (tid < BNODES) scan[tid] += v;
        __syncthreads();
    }
    if (tid < BNODES) cur[tid] = scan[tid] - hist[tid];   // exclusive
    __syncthreads();
    for (int e = tid; e < cnt; e += 256) {
        uint_t r = rec[e];
        int p = atomicAdd(&cur[r >> 20], 1);   // int LDS atomic: native
        srt[p] = r & 0xFFFFF;
    }
    __syncthreads();
    uint_t* cs = &colsort[(size_t)b * BCAP];
    for (int e = tid; e < cnt; e += 256) cs[e] = srt[e];
    if (tid < BNODES) {
        rp[b * (BNODES + 1) + tid] = scan[tid] - hist[tid];
        int n = b * BNODES + tid;
        if (n < N) dinv[n] = rsqrtf((float)hist[tid] + 1.0f);
    }
    if (tid == 0) rp[b * (BNODES + 1) + BNODES] = cnt;
}

// ---------------- fused weight transpose -> bf16 -----------------------------
// T2,T3 rows permuted on k: phys kp -> logical k = (kp>>5)*32 + ((kp&1)<<4) + ((kp&31)>>1)

__global__ __launch_bounds__(256) void k_wtall(const float* __restrict__ W1,
                                               const float* __restrict__ W2,
                                               const float* __restrict__ W3,
                                               ushort_t* __restrict__ T1,
                                               ushort_t* __restrict__ T2,
                                               ushort_t* __restrict__ T3) {
    int idx = blockIdx.x * 256 + threadIdx.x;
    if (idx < NHID * NFEAT) {                                // T1[128][256] (no perm)
        int nrow = idx >> 8, k = idx & 255;
        T1[idx] = f2bf(W1[(size_t)k * NHID + nrow]);
    } else if ((idx -= NHID * NFEAT) < NHID * NHID) {        // T2[128][128] k-perm
        int nrow = idx >> 7, kp = idx & 127;
        int s = kp >> 5, pl = kp & 31;
        int k = s * 32 + ((pl & 1) << 4) + (pl >> 1);
        T2[idx] = f2bf(W2[(size_t)k * NHID + nrow]);
    } else if ((idx -= NHID * NHID) < 64 * NHID) {           // T3[64][128] k-perm, pad
        int nrow = idx >> 7, kp = idx & 127;
        int s = kp >> 5, pl = kp & 31;
        int k = s * 32 + ((pl & 1) << 4) + (pl >> 1);
        T3[idx] = f2bf(nrow < NCLASS ? W3[(size_t)k * NCLASS + nrow] : 0.f);
    }
}

// ---------------- MFMA GEMM (bf16 weights, BM=128, 512 thr / 8 waves) -------
// C = (A @ W) * dinv[row]   (pre-scaled h')
// MODE 0: out fp8 e4m3, slice-major [2][N][64] (64B rows), byte-pair packed
// MODE 1: out bf16 row-major [N][OST]
// A_FP32: A row-major fp32 (convert path); else A bf16 phys-order [2][N][64]

template<int K, bool A_FP32, int BN, int OST, int MODE>
__global__ __launch_bounds__(512) void k_gemm_mfma(const void* __restrict__ Ap,
                                                   const ushort_t* __restrict__ Whi,
                                                   const float* __restrict__ dinv,
                                                   void* __restrict__ Cv, int n) {
    const int BM = 128, BK = 64;
    __shared__ ushort_t As[BM * BK];
    __shared__ ushort_t Bh[BN * BK];
    const int tid = threadIdx.x;
    const int w = tid >> 6, l = tid & 63;
    const int row0 = blockIdx.x * BM;
    const int NJ = BN / 16;
    f32x4 acc[NJ] = {};

    for (int k0 = 0; k0 < K; k0 += BK) {
        // ---- stage A tile (128 x 64) ----
        if (A_FP32) {
            int r = tid >> 2;                       // 0..127
            if (row0 + r < n) {
                const float* A = (const float*)Ap;
                const float* ap = &A[(size_t)(row0 + r) * K + k0];
#pragma unroll
                for (int h = 0; h < 2; h++) {
                    int q = (tid & 3) * 2 + h;
                    float4 v0 = *(const float4*)&ap[q * 8];
                    float4 v1 = *(const float4*)&ap[q * 8 + 4];
                    ushort4 o0, o1;
                    o0.x = f2bf(v0.x); o0.y = f2bf(v0.y); o0.z = f2bf(v0.z); o0.w = f2bf(v0.w);
                    o1.x = f2bf(v1.x); o1.y = f2bf(v1.y); o1.z = f2bf(v1.z); o1.w = f2bf(v1.w);
                    int pc = q ^ (r & 7);
                    *(ushort4*)&As[r * 64 + pc * 8]     = o0;
                    *(ushort4*)&As[r * 64 + pc * 8 + 4] = o1;
                }
            }
        } else {
            const ushort_t* A = (const ushort_t*)Ap;
#pragma unroll
            for (int m = 0; m < 2; m++) {           // 1024 chunks, 2 rounds of 512
                int unit = m * 512 + tid;
                int r = unit >> 3, pc = unit & 7;
                int lc = pc ^ (r & 7);
                int kk = k0 + lc * 8;
                size_t rowg = (size_t)min(row0 + r, n - 1);   // clamp: junk rows unused
                const ushort_t* srcp = &A[(size_t)(kk >> 6) * n * 64 + rowg * 64 + (kk & 63)];
                gload16(srcp, &As[(size_t)unit * 8]);
            }
        }
        // ---- stage B tile (BN x 64): BN*8 chunks, BN/64 rounds of 512 ----
#pragma unroll
        for (int m = 0; m < BN / 64; m++) {
            int unit = m * 512 + tid;
            int r = unit >> 3, pc = unit & 7;
            int lc = pc ^ (r & 7);
            gload16(&Whi[(size_t)r * K + k0 + lc * 8], &Bh[(size_t)unit * 8]);
        }
        __syncthreads();   // drains vmcnt + lgkmcnt

        const int lo4 = l & 15;
        const int swz = l & 7;
#pragma unroll
        for (int kh = 0; kh < BK; kh += 32) {
            int q = (kh >> 3) + (l >> 4);
            int ra = w * 16 + lo4;
            bf16x8 a = *(const bf16x8*)&As[ra * 64 + (q ^ swz) * 8];
#pragma unroll
            for (int j = 0; j < NJ; j++) {
                int rb = j * 16 + lo4;
                bf16x8 bh = *(const bf16x8*)&Bh[rb * 64 + (q ^ swz) * 8];
                acc[j] = __builtin_amdgcn_mfma_f32_16x16x32_bf16(a, bh, acc[j], 0, 0, 0);
            }
        }
        __syncthreads();
    }

    float dnv[4];
#pragma unroll
    for (int r = 0; r < 4; r++) {
        int row = row0 + w * 16 + (l >> 4) * 4 + r;
        dnv[r] = (row < n) ? dinv[row] : 0.f;
    }
    const int cb = l & 15;
    if (MODE == 0) {
        // fp8 pack: old slice s = 2t+sub -> row t, bytes sub*32 + {2cb, 2cb+1}
        uchar_t* C8 = (uchar_t*)Cv;
#pragma unroll
        for (int s = 0; s < NJ / 2; s++) {
            int t = s >> 1, sub = s & 1;
#pragma unroll
            for (int r = 0; r < 4; r++) {
                int row = row0 + w * 16 + (l >> 4) * 4 + r;
                if (row < n) {
                    ushort_t pk = pk2fp8(dnv[r] * acc[2 * s][r], dnv[r] * acc[2 * s + 1][r]);
                    *(ushort_t*)&C8[(size_t)t * n * 64 + (size_t)row * 64 + sub * 32 + cb * 2] = pk;
                }
            }
        }
    } else {
        ushort_t* C = (ushort_t*)Cv;
#pragma unroll
        for (int j = 0; j < NJ; j++) {
#pragma unroll
            for (int r = 0; r < 4; r++) {
                int row = row0 + w * 16 + (l >> 4) * 4 + r;
                if (row < n)
                    C[(size_t)row * OST + j * 16 + cb] = f2bf(dnv[r] * acc[j][r]);
            }
        }
    }
}

// ---------------- sliced aggregation (layers 1,2) — fp8 64B rows, XCD-affine -
// grid padded to mult of 8: m=blk>>3, j=blk&7 -> slice=j>>2, bucket=m*4+(j&3)
// XCDs 0-3 see only slice 0, XCDs 4-7 only slice 1 (halved per-XCD footprint)

__global__ __launch_bounds__(256) void k_agg_slice(const uint_t* __restrict__ colsort,
                                                   const int* __restrict__ rp,
                                                   const uchar_t* __restrict__ h8,
                                                   const float* __restrict__ dinv,
                                                   const float* __restrict__ bias,
                                                   ushort_t* __restrict__ out, int N,
                                                   int NBKtot) {
    __shared__ int srp[BNODES + 1];
    __shared__ uint_t cols[BCAP];
    int blk = blockIdx.x;
    int slice = (blk >> 2) & 1;
    int b = (blk >> 3) * 4 + (blk & 3);
    if (b >= NBKtot) return;
    int tid = threadIdx.x;
    if (tid <= BNODES) srp[tid] = rp[b * (BNODES + 1) + tid];
    __syncthreads();
    int cnt = srp[BNODES];
    for (int e = tid; e < cnt; e += 256) cols[e] = colsort[(size_t)b * BCAP + e];
    __syncthreads();
    int fq = tid & 3;                  // 16B quarter of the 64B row (16 fp8 feats)
    int q  = tid >> 2;                 // node slot 0..63
    const uchar_t* hs = &h8[(size_t)slice * N * 64 + fq * 16];
    // bias for phys byte p = fq*16+i : s = 2*slice + (p>>5), pl = p&31,
    // logical c = s*32 + ((pl&1)<<4) + (pl>>1)
    float bv[16];
#pragma unroll
    for (int i = 0; i < 16; i++) {
        int p = fq * 16 + i;
        int s = 2 * slice + (p >> 5), pl = p & 31;
        bv[i] = bias[s * 32 + ((pl & 1) << 4) + (pl >> 1)];
    }
    for (int nl = q; nl < BNODES; nl += 64) {
        int n = b * BNODES + nl;
        if (n >= N) break;
        int e = srp[nl], e1 = srp[nl + 1];
        f32x2 a2[8];
        {
            uint4 sv = *(const uint4*)&hs[(size_t)n * 64];
            a2[0] = unpk_lo(sv.x); a2[1] = unpk_hi(sv.x);
            a2[2] = unpk_lo(sv.y); a2[3] = unpk_hi(sv.y);
            a2[4] = unpk_lo(sv.z); a2[5] = unpk_hi(sv.z);
            a2[6] = unpk_lo(sv.w); a2[7] = unpk_hi(sv.w);
        }
        for (; e + 4 <= e1; e += 4) {
            uint4 v[4];
#pragma unroll
            for (int i = 0; i < 4; i++) v[i] = *(const uint4*)&hs[(size_t)cols[e + i] * 64];
#pragma unroll
            for (int i = 0; i < 4; i++) {
                a2[0] += unpk_lo(v[i].x); a2[1] += unpk_hi(v[i].x);
                a2[2] += unpk_lo(v[i].y); a2[3] += unpk_hi(v[i].y);
                a2[4] += unpk_lo(v[i].z); a2[5] += unpk_hi(v[i].z);
                a2[6] += unpk_lo(v[i].w); a2[7] += unpk_hi(v[i].w);
            }
        }
        for (; e < e1; e++) {
            uint4 v = *(const uint4*)&hs[(size_t)cols[e] * 64];
            a2[0] += unpk_lo(v.x); a2[1] += unpk_hi(v.x);
            a2[2] += unpk_lo(v.y); a2[3] += unpk_hi(v.y);
            a2[4] += unpk_lo(v.z); a2[5] += unpk_hi(v.z);
            a2[6] += unpk_lo(v.w); a2[7] += unpk_hi(v.w);
        }
        float dn = dinv[n];
        uint_t o[8];
#pragma unroll
        for (int k = 0; k < 8; k++) {
            float r0 = fmaxf(fmaf(dn, a2[k].x, bv[2 * k]),     0.f);
            float r1 = fmaxf(fmaf(dn, a2[k].y, bv[2 * k + 1]), 0.f);
            o[k] = ((uint_t)f2bf(r1) << 16) | f2bf(r0);
        }
        ushort_t* op = &out[((size_t)slice * N + n) * 64 + fq * 16];
        *(uint4*)&op[0] = make_uint4(o[0], o[1], o[2], o[3]);
        *(uint4*)&op[8] = make_uint4(o[4], o[5], o[6], o[7]);
    }
}

// ---------------- layer-3 aggregation + log_softmax — padded 128B rows ------

__global__ __launch_bounds__(256) void k_agg40_lsm(const uint_t* __restrict__ colsort,
                                                   const int* __restrict__ rp,
                                                   const ushort_t* __restrict__ h3,
                                                   const float* __restrict__ dinv,
                                                   const float* __restrict__ bias,
                                                   float* __restrict__ out, int N) {
    __shared__ int srp[BNODES + 1];
    __shared__ uint_t cols[BCAP];
    int b = blockIdx.x, tid = threadIdx.x;
    if (tid <= BNODES) srp[tid] = rp[b * (BNODES + 1) + tid];
    __syncthreads();
    int cnt = srp[BNODES];
    for (int e = tid; e < cnt; e += 256) cols[e] = colsort[(size_t)b * BCAP + e];
    __syncthreads();
    int fo = tid & 7;                  // feature octant (8 feats, 16B)
    int g  = tid >> 3;                 // node slot 0..31
    bool act = fo < 5;
    float bv[8];
#pragma unroll
    for (int j = 0; j < 8; j++) bv[j] = act ? bias[fo * 8 + j] : 0.f;
    for (int nl = g; nl < BNODES; nl += 32) {
        int n = b * BNODES + nl;
        if (n >= N) break;
        int e = srp[nl], e1 = srp[nl + 1];
        float a[8] = {0.f, 0.f, 0.f, 0.f, 0.f, 0.f, 0.f, 0.f};
        if (act) {
            uint4 sv = *(const uint4*)&h3[(size_t)n * 64 + fo * 8];
            a[0] = lo2f(sv.x); a[1] = hi2f(sv.x); a[2] = lo2f(sv.y); a[3] = hi2f(sv.y);
            a[4] = lo2f(sv.z); a[5] = hi2f(sv.z); a[6] = lo2f(sv.w); a[7] = hi2f(sv.w);
        }
        for (; e + 4 <= e1; e += 4) {
            if (act) {
                uint4 v[4];
#pragma unroll
                for (int i = 0; i < 4; i++) v[i] = *(const uint4*)&h3[(size_t)cols[e + i] * 64 + fo * 8];
#pragma unroll
                for (int i = 0; i < 4; i++) {
                    a[0] = dot2bf(v[i].x, LOMASK, a[0]); a[1] = dot2bf(v[i].x, HIMASK, a[1]);
                    a[2] = dot2bf(v[i].y, LOMASK, a[2]); a[3] = dot2bf(v[i].y, HIMASK, a[3]);
                    a[4] = dot2bf(v[i].z, LOMASK, a[4]); a[5] = dot2bf(v[i].z, HIMASK, a[5]);
                    a[6] = dot2bf(v[i].w, LOMASK, a[6]); a[7] = dot2bf(v[i].w, HIMASK, a[7]);
                }
            }
        }
        for (; e < e1; e++) {
            if (act) {
                uint4 v = *(const uint4*)&h3[(size_t)cols[e] * 64 + fo * 8];
                a[0] = dot2bf(v.x, LOMASK, a[0]); a[1] = dot2bf(v.x, HIMASK, a[1]);
                a[2] = dot2bf(v.y, LOMASK, a[2]); a[3] = dot2bf(v.y, HIMASK, a[3]);
                a[4] = dot2bf(v.z, LOMASK, a[4]); a[5] = dot2bf(v.z, HIMASK, a[5]);
                a[6] = dot2bf(v.w, LOMASK, a[6]); a[7] = dot2bf(v.w, HIMASK, a[7]);
            }
        }
        float dn = dinv[n];
        float z[8];
        float m = -INFINITY;
#pragma unroll
        for (int j = 0; j < 8; j++) {
            z[j] = act ? fmaf(dn, a[j], bv[j]) : -INFINITY;
            m = fmaxf(m, z[j]);
        }
#pragma unroll
        for (int off = 4; off; off >>= 1) m = fmaxf(m, __shfl_xor(m, off, 8));
        float p = 0.f;
        if (act) {
#pragma unroll
            for (int j = 0; j < 8; j++) p += expf(z[j] - m);
        }
#pragma unroll
        for (int off = 4; off; off >>= 1) p += __shfl_xor(p, off, 8);
        float lse = m + logf(p);
        if (act) {
            float4 o0 = make_float4(z[0] - lse, z[1] - lse, z[2] - lse, z[3] - lse);
            float4 o1 = make_float4(z[4] - lse, z[5] - lse, z[6] - lse, z[7] - lse);
            *(float4*)&out[(size_t)n * NCLASS + fo * 8]     = o0;
            *(float4*)&out[(size_t)n * NCLASS + fo * 8 + 4] = o1;
        }
    }
}

// ---------------- launch ----------------

extern "C" void kernel_launch(void* const* d_in, const int* in_sizes, int n_in,
                              void* d_out, int out_size, void* d_ws, size_t ws_size,
                              hipStream_t stream) {
    const float* x  = (const float*)d_in[0];
    const int*   ei = (const int*)d_in[1];
    const float* W1 = (const float*)d_in[2];
    const float* b1 = (const float*)d_in[3];
    const float* W2 = (const float*)d_in[4];
    const float* b2 = (const float*)d_in[5];
    const float* W3 = (const float*)d_in[6];
    const float* b3 = (const float*)d_in[7];
    float* out = (float*)d_out;
    const int N = in_sizes[0] / NFEAT;
    const int E = in_sizes[1] / 2;
    const int* src = ei;
    const int* dst = ei + E;
    const int NBK = (N + BNODES - 1) / BNODES;
    const int NBLK_E = (E + EPB - 1) / EPB;

    char* ws = (char*)d_ws;
    size_t off = 0;
    auto alloc = [&](size_t bytes) -> void* {
        void* p = ws + off;
        off += (bytes + 255) & ~(size_t)255;
        return p;
    };
    int*      bcnt    = (int*)alloc((size_t)NBK * 4);
    int*      ecnt    = (int*)alloc((size_t)NBK * NBLK_E * 4);
    uint_t*   bstore  = (uint_t*)alloc((size_t)NBK * BCAP * 4);
    uint_t*   colsort = (uint_t*)alloc((size_t)NBK * BCAP * 4);
    int*      rp      = (int*)alloc((size_t)NBK * (BNODES + 1) * 4);
    float*    dinv    = (float*)alloc((size_t)N * 4);
    uchar_t*  h8      = (uchar_t*)alloc((size_t)N * NHID);       // fp8 GEMM out [2][N][64]
    ushort_t* abuf    = (ushort_t*)alloc((size_t)N * NHID * 2);  // bf16 agg out [2][N][64]
    ushort_t* h3      = (ushort_t*)alloc((size_t)N * 64 * 2);    // padded [N][64] bf16
    ushort_t* Whi1    = (ushort_t*)alloc((size_t)NHID * NFEAT * 2);
    ushort_t* Whi2    = (ushort_t*)alloc((size_t)NHID * NHID * 2);
    ushort_t* Whi3    = (ushort_t*)alloc((size_t)64 * NHID * 2);
    (void)ws_size; (void)n_in; (void)out_size;

    // fused weight prep (T2/T3 k-permuted to match fp8 byte-pair order)
    int wtelems = NHID * NFEAT + NHID * NHID + 64 * NHID;
    k_wtall<<<(wtelems + 255) / 256, 256, 0, stream>>>(W1, W2, W3, Whi1, Whi2, Whi3);

    // edge partition (no global atomics) + per-bucket sort + dinv
    k_ehist<<<NBLK_E, 256, 0, stream>>>(dst, ecnt, E, NBK, NBLK_E);
    k_escan<<<NBK, 128, 0, stream>>>(ecnt, bcnt, NBLK_E);
    k_escatter<<<NBLK_E, 256, 0, stream>>>(src, dst, ecnt, bstore, E, NBK, NBLK_E);
    k_bsort<<<NBK, 256, 0, stream>>>(bstore, bcnt, colsort, rp, dinv, N);

    int ngemm = (N + 127) / 128;
    int naggs = ((2 * NBK + 7) / 8) * 8;   // padded to mult of 8 for XCD-affine map
    // layer 1
    k_gemm_mfma<NFEAT, true, 128, 0, 0><<<ngemm, 512, 0, stream>>>(x, Whi1, dinv, h8, N);
    k_agg_slice<<<naggs, 256, 0, stream>>>(colsort, rp, h8, dinv, b1, abuf, N, NBK);
    // layer 2
    k_gemm_mfma<NHID, false, 128, 0, 0><<<ngemm, 512, 0, stream>>>(abuf, Whi2, dinv, h8, N);
    k_agg_slice<<<naggs, 256, 0, stream>>>(colsort, rp, h8, dinv, b2, abuf, N, NBK);
    // layer 3 + log_softmax
    k_gemm_mfma<NHID, false, 64, 64, 1><<<ngemm, 512, 0, stream>>>(abuf, Whi3, dinv, h3, N);
    k_agg40_lsm<<<NBK, 256, 0, stream>>>(colsort, rp, h3, dinv, b3, out, N);
}

// Round 19
// 212.680 us; speedup vs baseline: 1.1267x; 1.1267x over previous
//
#include <hip/hip_runtime.h>
#include <math.h>

#define NFEAT 256
#define NHID 128
#define NCLASS 40
#define BNODES 128
#define BSHIFT 7
#define BCAP 2688
#define MAXBK 1024
#define EPB 8192

typedef unsigned short ushort_t;
typedef unsigned int uint_t;
typedef unsigned char uchar_t;
typedef __attribute__((ext_vector_type(8))) short bf16x8;
typedef __attribute__((ext_vector_type(4))) float f32x4;
typedef __attribute__((ext_vector_type(2))) float f32x2;

static __device__ inline float bf2f(ushort_t u) {
    union { uint_t u; float f; } v; v.u = (uint_t)u << 16; return v.f;
}
static __device__ inline float lo2f(uint_t u) {
    union { uint_t u; float f; } v; v.u = u << 16; return v.f;
}
static __device__ inline float hi2f(uint_t u) {
    union { uint_t u; float f; } v; v.u = u & 0xFFFF0000u; return v.f;
}
static __device__ inline ushort_t f2bf(float f) {
    uint_t u = __float_as_uint(f);
    u += 0x7FFF + ((u >> 16) & 1);           // round-to-nearest-even
    return (ushort_t)(u >> 16);
}
// fused bf16-extract + fp32 accumulate
static __device__ inline float dot2bf(uint_t pk, uint_t mask, float c) {
    float r;
    asm("v_dot2_f32_bf16 %0, %1, %2, %3" : "=v"(r) : "v"(pk), "v"(mask), "v"(c));
    return r;
}
#define LOMASK 0x00003F80u
#define HIMASK 0x3F800000u

// async global->LDS 16B (dest = wave-uniform base + lane*16)
static __device__ __forceinline__ void gload16(const void* g, void* l) {
    __builtin_amdgcn_global_load_lds(
        (const __attribute__((address_space(1))) uint_t*)g,
        (__attribute__((address_space(3))) uint_t*)l, 16, 0, 0);
}

// fp8 e4m3 pack/unpack (gfx950 native)
static __device__ inline ushort_t pk2fp8(float a, float b) {
    return (ushort_t)__builtin_amdgcn_cvt_pk_fp8_f32(a, b, 0, false);
}
static __device__ inline f32x2 unpk_lo(uint_t w) {
    return __builtin_amdgcn_cvt_pk_f32_fp8(w, false);
}
static __device__ inline f32x2 unpk_hi(uint_t w) {
    return __builtin_amdgcn_cvt_pk_f32_fp8(w, true);
}

// ---------------- edge partition by dst-bucket: hist / scan / scatter --------

__global__ __launch_bounds__(256) void k_ehist(const int* __restrict__ dst,
                                               int* __restrict__ cnt,
                                               int E, int nbk, int nblk) {
    __shared__ int hist[MAXBK];
    int tid = threadIdx.x, be = blockIdx.x;
    for (int i = tid; i < nbk; i += 256) hist[i] = 0;
    __syncthreads();
    int e0 = be * EPB, e1 = min(e0 + EPB, E);
    for (int e = e0 + tid; e < e1; e += 256)
        atomicAdd(&hist[dst[e] >> BSHIFT], 1);          // LDS int atomic: native
    __syncthreads();
    for (int i = tid; i < nbk; i += 256)
        cnt[(size_t)i * nblk + be] = hist[i];
}

__global__ __launch_bounds__(256) void k_escan(int* __restrict__ cnt,
                                               int* __restrict__ bcnt, int nblk) {
    __shared__ int buf[256];
    int b = blockIdx.x, tid = threadIdx.x;
    int v = (tid < nblk) ? cnt[(size_t)b * nblk + tid] : 0;
    buf[tid] = v;
    __syncthreads();
    for (int off = 1; off < 256; off <<= 1) {
        int t = (tid >= off) ? buf[tid - off] : 0;
        __syncthreads();
        buf[tid] += t;
        __syncthreads();
    }
    if (tid < nblk) cnt[(size_t)b * nblk + tid] = buf[tid] - v;   // exclusive
    if (tid == 255) bcnt[b] = buf[255];                           // total
}

// block-local counting sort -> coalesced run writes (replaces 4B scatter)
__global__ __launch_bounds__(256) void k_escatter(const int* __restrict__ src,
                                                  const int* __restrict__ dst,
                                                  const int* __restrict__ cnt,
                                                  uint_t* __restrict__ bstore,
                                                  int E, int nbk, int nblk) {
    __shared__ uint_t   sorted[EPB];     // 32 KB
    __shared__ ushort_t sortb[EPB];      // 16 KB
    __shared__ int hist[MAXBK];          // 4 KB
    __shared__ int lcur[MAXBK];          // 4 KB
    __shared__ int gadj[MAXBK];          // 4 KB
    __shared__ int buf[256];             // 1 KB
    int tid = threadIdx.x, be = blockIdx.x;
    for (int i = tid; i < MAXBK; i += 256) hist[i] = 0;
    __syncthreads();
    int e0 = be * EPB, e1 = min(e0 + EPB, E);
    // pass 1: local bucket histogram
    for (int e = e0 + tid; e < e1; e += 256)
        atomicAdd(&hist[dst[e] >> BSHIFT], 1);
    __syncthreads();
    // exclusive scan over MAXBK (each thread owns 4 slots)
    int base = tid * 4;
    int v0 = hist[base], v1 = hist[base + 1], v2 = hist[base + 2], v3 = hist[base + 3];
    int s = v0 + v1 + v2 + v3;
    buf[tid] = s;
    __syncthreads();
    for (int off = 1; off < 256; off <<= 1) {
        int t = (tid >= off) ? buf[tid - off] : 0;
        __syncthreads();
        buf[tid] += t;
        __syncthreads();
    }
    int run = buf[tid] - s;
    int ls0 = run, ls1 = run + v0, ls2 = run + v0 + v1, ls3 = run + v0 + v1 + v2;
    gadj[base]     = ((base     < nbk) ? cnt[(size_t)(base)     * nblk + be] : 0) - ls0;
    gadj[base + 1] = ((base + 1 < nbk) ? cnt[(size_t)(base + 1) * nblk + be] : 0) - ls1;
    gadj[base + 2] = ((base + 2 < nbk) ? cnt[(size_t)(base + 2) * nblk + be] : 0) - ls2;
    gadj[base + 3] = ((base + 3 < nbk) ? cnt[(size_t)(base + 3) * nblk + be] : 0) - ls3;
    lcur[base] = ls0; lcur[base + 1] = ls1; lcur[base + 2] = ls2; lcur[base + 3] = ls3;
    __syncthreads();
    // pass 2: scatter into local sorted order
    for (int e = e0 + tid; e < e1; e += 256) {
        int d = dst[e];
        int b = d >> BSHIFT;
        uint_t rec = ((uint_t)(d & (BNODES - 1)) << 20) | (uint_t)src[e];
        int p = atomicAdd(&lcur[b], 1);              // LDS int atomic: native
        sorted[p] = rec;
        sortb[p] = (ushort_t)b;
    }
    __syncthreads();
    // pass 3: coalesced run writes
    int cntL = e1 - e0;
    for (int i = tid; i < cntL; i += 256) {
        int bb = sortb[i];
        int idx = gadj[bb] + i;                      // index within bucket
        if (idx < BCAP)
            bstore[(size_t)bb * BCAP + idx] = sorted[i];
    }
}

// ---------------- per-bucket counting sort (LDS), + rp + dinv ----------------

__global__ __launch_bounds__(256) void k_bsort(const uint_t* __restrict__ bstore,
                                               const int* __restrict__ bcnt,
                                               uint_t* __restrict__ colsort,
                                               int* __restrict__ rp,
                                               float* __restrict__ dinv, int N) {
    __shared__ uint_t rec[BCAP];
    __shared__ uint_t srt[BCAP];
    __shared__ int hist[BNODES];
    __shared__ int scan[BNODES];
    __shared__ int cur[BNODES];
    int b = blockIdx.x, tid = threadIdx.x;
    if (tid < BNODES) hist[tid] = 0;
    __syncthreads();
    int cnt = min(bcnt[b], BCAP);
    const uint_t* gp = &bstore[(size_t)b * BCAP];
    for (int e = tid; e < cnt; e += 256) {
        uint_t r = gp[e];
        rec[e] = r;
        atomicAdd(&hist[r >> 20], 1);          // int LDS atomic: native
    }
    __syncthreads();
    if (tid < BNODES) scan[tid] = hist[tid];
    __syncthreads();
    for (int off = 1; off < BNODES; off <<= 1) {
        int v = 0;
        if (tid < BNODES && tid >= off) v = scan[tid - off];
        __syncthreads();
        if (tid < BNODES) scan[tid] += v;
        __syncthreads();
    }
    if (tid < BNODES) cur[tid] = scan[tid] - hist[tid];   // exclusive
    __syncthreads();
    for (int e = tid; e < cnt; e += 256) {
        uint_t r = rec[e];
        int p = atomicAdd(&cur[r >> 20], 1);   // int LDS atomic: native
        srt[p] = r & 0xFFFFF;
    }
    __syncthreads();
    uint_t* cs = &colsort[(size_t)b * BCAP];
    for (int e = tid; e < cnt; e += 256) cs[e] = srt[e];
    if (tid < BNODES) {
        rp[b * (BNODES + 1) + tid] = scan[tid] - hist[tid];
        int n = b * BNODES + tid;
        if (n < N) dinv[n] = rsqrtf((float)hist[tid] + 1.0f);
    }
    if (tid == 0) rp[b * (BNODES + 1) + BNODES] = cnt;
}

// ---------------- fused weight transpose -> bf16 -----------------------------
// T2,T3 rows permuted on k: phys kp -> logical k = (kp>>5)*32 + ((kp&1)<<4) + ((kp&31)>>1)

__global__ __launch_bounds__(256) void k_wtall(const float* __restrict__ W1,
                                               const float* __restrict__ W2,
                                               const float* __restrict__ W3,
                                               ushort_t* __restrict__ T1,
                                               ushort_t* __restrict__ T2,
                                               ushort_t* __restrict__ T3) {
    int idx = blockIdx.x * 256 + threadIdx.x;
    if (idx < NHID * NFEAT) {                                // T1[128][256] (no perm)
        int nrow = idx >> 8, k = idx & 255;
        T1[idx] = f2bf(W1[(size_t)k * NHID + nrow]);
    } else if ((idx -= NHID * NFEAT) < NHID * NHID) {        // T2[128][128] k-perm
        int nrow = idx >> 7, kp = idx & 127;
        int s = kp >> 5, pl = kp & 31;
        int k = s * 32 + ((pl & 1) << 4) + (pl >> 1);
        T2[idx] = f2bf(W2[(size_t)k * NHID + nrow]);
    } else if ((idx -= NHID * NHID) < 64 * NHID) {           // T3[64][128] k-perm, pad
        int nrow = idx >> 7, kp = idx & 127;
        int s = kp >> 5, pl = kp & 31;
        int k = s * 32 + ((pl & 1) << 4) + (pl >> 1);
        T3[idx] = f2bf(nrow < NCLASS ? W3[(size_t)k * NCLASS + nrow] : 0.f);
    }
}

// ---------------- MFMA GEMM (bf16 weights, BM=128, 512 thr / 8 waves) -------
// C = (A @ W) * dinv[row]   (pre-scaled h')
// MODE 0: out fp8 e4m3, slice-major [2][N][64] (64B rows), byte-pair packed
// MODE 1: out bf16 row-major [N][OST]
// A_FP32: A row-major fp32 (convert path); else A bf16 phys-order [2][N][64]

template<int K, bool A_FP32, int BN, int OST, int MODE>
__global__ __launch_bounds__(512) void k_gemm_mfma(const void* __restrict__ Ap,
                                                   const ushort_t* __restrict__ Whi,
                                                   const float* __restrict__ dinv,
                                                   void* __restrict__ Cv, int n) {
    const int BM = 128, BK = 64;
    __shared__ ushort_t As[BM * BK];
    __shared__ ushort_t Bh[BN * BK];
    const int tid = threadIdx.x;
    const int w = tid >> 6, l = tid & 63;
    const int row0 = blockIdx.x * BM;
    const int NJ = BN / 16;
    f32x4 acc[NJ] = {};

    for (int k0 = 0; k0 < K; k0 += BK) {
        // ---- stage A tile (128 x 64) ----
        if (A_FP32) {
            int r = tid >> 2;                       // 0..127
            if (row0 + r < n) {
                const float* A = (const float*)Ap;
                const float* ap = &A[(size_t)(row0 + r) * K + k0];
#pragma unroll
                for (int h = 0; h < 2; h++) {
                    int q = (tid & 3) * 2 + h;
                    float4 v0 = *(const float4*)&ap[q * 8];
                    float4 v1 = *(const float4*)&ap[q * 8 + 4];
                    ushort4 o0, o1;
                    o0.x = f2bf(v0.x); o0.y = f2bf(v0.y); o0.z = f2bf(v0.z); o0.w = f2bf(v0.w);
                    o1.x = f2bf(v1.x); o1.y = f2bf(v1.y); o1.z = f2bf(v1.z); o1.w = f2bf(v1.w);
                    int pc = q ^ (r & 7);
                    *(ushort4*)&As[r * 64 + pc * 8]     = o0;
                    *(ushort4*)&As[r * 64 + pc * 8 + 4] = o1;
                }
            }
        } else {
            const ushort_t* A = (const ushort_t*)Ap;
#pragma unroll
            for (int m = 0; m < 2; m++) {           // 1024 chunks, 2 rounds of 512
                int unit = m * 512 + tid;
                int r = unit >> 3, pc = unit & 7;
                int lc = pc ^ (r & 7);
                int kk = k0 + lc * 8;
                size_t rowg = (size_t)min(row0 + r, n - 1);   // clamp: junk rows unused
                const ushort_t* srcp = &A[(size_t)(kk >> 6) * n * 64 + rowg * 64 + (kk & 63)];
                gload16(srcp, &As[(size_t)unit * 8]);
            }
        }
        // ---- stage B tile (BN x 64): BN*8 chunks, BN/64 rounds of 512 ----
#pragma unroll
        for (int m = 0; m < BN / 64; m++) {
            int unit = m * 512 + tid;
            int r = unit >> 3, pc = unit & 7;
            int lc = pc ^ (r & 7);
            gload16(&Whi[(size_t)r * K + k0 + lc * 8], &Bh[(size_t)unit * 8]);
        }
        __syncthreads();   // drains vmcnt + lgkmcnt

        const int lo4 = l & 15;
        const int swz = l & 7;
#pragma unroll
        for (int kh = 0; kh < BK; kh += 32) {
            int q = (kh >> 3) + (l >> 4);
            int ra = w * 16 + lo4;
            bf16x8 a = *(const bf16x8*)&As[ra * 64 + (q ^ swz) * 8];
#pragma unroll
            for (int j = 0; j < NJ; j++) {
                int rb = j * 16 + lo4;
                bf16x8 bh = *(const bf16x8*)&Bh[rb * 64 + (q ^ swz) * 8];
                acc[j] = __builtin_amdgcn_mfma_f32_16x16x32_bf16(a, bh, acc[j], 0, 0, 0);
            }
        }
        __syncthreads();
    }

    float dnv[4];
#pragma unroll
    for (int r = 0; r < 4; r++) {
        int row = row0 + w * 16 + (l >> 4) * 4 + r;
        dnv[r] = (row < n) ? dinv[row] : 0.f;
    }
    const int cb = l & 15;
    if (MODE == 0) {
        // fp8 pack: old slice s = 2t+sub -> row t, bytes sub*32 + {2cb, 2cb+1}
        uchar_t* C8 = (uchar_t*)Cv;
#pragma unroll
        for (int s = 0; s < NJ / 2; s++) {
            int t = s >> 1, sub = s & 1;
#pragma unroll
            for (int r = 0; r < 4; r++) {
                int row = row0 + w * 16 + (l >> 4) * 4 + r;
                if (row < n) {
                    ushort_t pk = pk2fp8(dnv[r] * acc[2 * s][r], dnv[r] * acc[2 * s + 1][r]);
                    *(ushort_t*)&C8[(size_t)t * n * 64 + (size_t)row * 64 + sub * 32 + cb * 2] = pk;
                }
            }
        }
    } else {
        ushort_t* C = (ushort_t*)Cv;
#pragma unroll
        for (int j = 0; j < NJ; j++) {
#pragma unroll
            for (int r = 0; r < 4; r++) {
                int row = row0 + w * 16 + (l >> 4) * 4 + r;
                if (row < n)
                    C[(size_t)row * OST + j * 16 + cb] = f2bf(dnv[r] * acc[j][r]);
            }
        }
    }
}

// ---------------- sliced aggregation (layers 1,2) — fp8 64B line rows -------
// block=(bucket,slice); slice=blk&1; h8 [2][N][64] fp8 (phys byte order)
// 4 lanes/node x uint4 = full 64B line; out bf16 [2][N][64] same phys order

__global__ __launch_bounds__(256) void k_agg_slice(const uint_t* __restrict__ colsort,
                                                   const int* __restrict__ rp,
                                                   const uchar_t* __restrict__ h8,
                                                   const float* __restrict__ dinv,
                                                   const float* __restrict__ bias,
                                                   ushort_t* __restrict__ out, int N) {
    __shared__ int srp[BNODES + 1];
    __shared__ uint_t cols[BCAP];
    int blk = blockIdx.x;
    int slice = blk & 1, b = blk >> 1;
    int tid = threadIdx.x;
    if (tid <= BNODES) srp[tid] = rp[b * (BNODES + 1) + tid];
    __syncthreads();
    int cnt = srp[BNODES];
    for (int e = tid; e < cnt; e += 256) cols[e] = colsort[(size_t)b * BCAP + e];
    __syncthreads();
    int fq = tid & 3;                  // 16B quarter of the 64B row (16 fp8 feats)
    int q  = tid >> 2;                 // node slot 0..63
    const uchar_t* hs = &h8[(size_t)slice * N * 64 + fq * 16];
    float bv[16];
#pragma unroll
    for (int i = 0; i < 16; i++) {
        int p = fq * 16 + i;
        int s = 2 * slice + (p >> 5), pl = p & 31;
        bv[i] = bias[s * 32 + ((pl & 1) << 4) + (pl >> 1)];
    }
    for (int nl = q; nl < BNODES; nl += 64) {
        int n = b * BNODES + nl;
        if (n >= N) break;
        int e = srp[nl], e1 = srp[nl + 1];
        f32x2 a2[8];
        {
            uint4 sv = *(const uint4*)&hs[(size_t)n * 64];
            a2[0] = unpk_lo(sv.x); a2[1] = unpk_hi(sv.x);
            a2[2] = unpk_lo(sv.y); a2[3] = unpk_hi(sv.y);
            a2[4] = unpk_lo(sv.z); a2[5] = unpk_hi(sv.z);
            a2[6] = unpk_lo(sv.w); a2[7] = unpk_hi(sv.w);
        }
        for (; e + 4 <= e1; e += 4) {
            uint4 v[4];
#pragma unroll
            for (int i = 0; i < 4; i++) v[i] = *(const uint4*)&hs[(size_t)cols[e + i] * 64];
#pragma unroll
            for (int i = 0; i < 4; i++) {
                a2[0] += unpk_lo(v[i].x); a2[1] += unpk_hi(v[i].x);
                a2[2] += unpk_lo(v[i].y); a2[3] += unpk_hi(v[i].y);
                a2[4] += unpk_lo(v[i].z); a2[5] += unpk_hi(v[i].z);
                a2[6] += unpk_lo(v[i].w); a2[7] += unpk_hi(v[i].w);
            }
        }
        for (; e < e1; e++) {
            uint4 v = *(const uint4*)&hs[(size_t)cols[e] * 64];
            a2[0] += unpk_lo(v.x); a2[1] += unpk_hi(v.x);
            a2[2] += unpk_lo(v.y); a2[3] += unpk_hi(v.y);
            a2[4] += unpk_lo(v.z); a2[5] += unpk_hi(v.z);
            a2[6] += unpk_lo(v.w); a2[7] += unpk_hi(v.w);
        }
        float dn = dinv[n];
        uint_t o[8];
#pragma unroll
        for (int k = 0; k < 8; k++) {
            float r0 = fmaxf(fmaf(dn, a2[k].x, bv[2 * k]),     0.f);
            float r1 = fmaxf(fmaf(dn, a2[k].y, bv[2 * k + 1]), 0.f);
            o[k] = ((uint_t)f2bf(r1) << 16) | f2bf(r0);
        }
        ushort_t* op = &out[((size_t)slice * N + n) * 64 + fq * 16];
        *(uint4*)&op[0] = make_uint4(o[0], o[1], o[2], o[3]);
        *(uint4*)&op[8] = make_uint4(o[4], o[5], o[6], o[7]);
    }
}

// ---------------- layer-3 aggregation + log_softmax — padded 128B rows ------

__global__ __launch_bounds__(256) void k_agg40_lsm(const uint_t* __restrict__ colsort,
                                                   const int* __restrict__ rp,
                                                   const ushort_t* __restrict__ h3,
                                                   const float* __restrict__ dinv,
                                                   const float* __restrict__ bias,
                                                   float* __restrict__ out, int N) {
    __shared__ int srp[BNODES + 1];
    __shared__ uint_t cols[BCAP];
    int b = blockIdx.x, tid = threadIdx.x;
    if (tid <= BNODES) srp[tid] = rp[b * (BNODES + 1) + tid];
    __syncthreads();
    int cnt = srp[BNODES];
    for (int e = tid; e < cnt; e += 256) cols[e] = colsort[(size_t)b * BCAP + e];
    __syncthreads();
    int fo = tid & 7;                  // feature octant (8 feats, 16B)
    int g  = tid >> 3;                 // node slot 0..31
    bool act = fo < 5;
    float bv[8];
#pragma unroll
    for (int j = 0; j < 8; j++) bv[j] = act ? bias[fo * 8 + j] : 0.f;
    for (int nl = g; nl < BNODES; nl += 32) {
        int n = b * BNODES + nl;
        if (n >= N) break;
        int e = srp[nl], e1 = srp[nl + 1];
        float a[8] = {0.f, 0.f, 0.f, 0.f, 0.f, 0.f, 0.f, 0.f};
        if (act) {
            uint4 sv = *(const uint4*)&h3[(size_t)n * 64 + fo * 8];
            a[0] = lo2f(sv.x); a[1] = hi2f(sv.x); a[2] = lo2f(sv.y); a[3] = hi2f(sv.y);
            a[4] = lo2f(sv.z); a[5] = hi2f(sv.z); a[6] = lo2f(sv.w); a[7] = hi2f(sv.w);
        }
        for (; e + 4 <= e1; e += 4) {
            if (act) {
                uint4 v[4];
#pragma unroll
                for (int i = 0; i < 4; i++) v[i] = *(const uint4*)&h3[(size_t)cols[e + i] * 64 + fo * 8];
#pragma unroll
                for (int i = 0; i < 4; i++) {
                    a[0] = dot2bf(v[i].x, LOMASK, a[0]); a[1] = dot2bf(v[i].x, HIMASK, a[1]);
                    a[2] = dot2bf(v[i].y, LOMASK, a[2]); a[3] = dot2bf(v[i].y, HIMASK, a[3]);
                    a[4] = dot2bf(v[i].z, LOMASK, a[4]); a[5] = dot2bf(v[i].z, HIMASK, a[5]);
                    a[6] = dot2bf(v[i].w, LOMASK, a[6]); a[7] = dot2bf(v[i].w, HIMASK, a[7]);
                }
            }
        }
        for (; e < e1; e++) {
            if (act) {
                uint4 v = *(const uint4*)&h3[(size_t)cols[e] * 64 + fo * 8];
                a[0] = dot2bf(v.x, LOMASK, a[0]); a[1] = dot2bf(v.x, HIMASK, a[1]);
                a[2] = dot2bf(v.y, LOMASK, a[2]); a[3] = dot2bf(v.y, HIMASK, a[3]);
                a[4] = dot2bf(v.z, LOMASK, a[4]); a[5] = dot2bf(v.z, HIMASK, a[5]);
                a[6] = dot2bf(v.w, LOMASK, a[6]); a[7] = dot2bf(v.w, HIMASK, a[7]);
            }
        }
        float dn = dinv[n];
        float z[8];
        float m = -INFINITY;
#pragma unroll
        for (int j = 0; j < 8; j++) {
            z[j] = act ? fmaf(dn, a[j], bv[j]) : -INFINITY;
            m = fmaxf(m, z[j]);
        }
#pragma unroll
        for (int off = 4; off; off >>= 1) m = fmaxf(m, __shfl_xor(m, off, 8));
        float p = 0.f;
        if (act) {
#pragma unroll
            for (int j = 0; j < 8; j++) p += expf(z[j] - m);
        }
#pragma unroll
        for (int off = 4; off; off >>= 1) p += __shfl_xor(p, off, 8);
        float lse = m + logf(p);
        if (act) {
            float4 o0 = make_float4(z[0] - lse, z[1] - lse, z[2] - lse, z[3] - lse);
            float4 o1 = make_float4(z[4] - lse, z[5] - lse, z[6] - lse, z[7] - lse);
            *(float4*)&out[(size_t)n * NCLASS + fo * 8]     = o0;
            *(float4*)&out[(size_t)n * NCLASS + fo * 8 + 4] = o1;
        }
    }
}

// ---------------- launch ----------------

extern "C" void kernel_launch(void* const* d_in, const int* in_sizes, int n_in,
                              void* d_out, int out_size, void* d_ws, size_t ws_size,
                              hipStream_t stream) {
    const float* x  = (const float*)d_in[0];
    const int*   ei = (const int*)d_in[1];
    const float* W1 = (const float*)d_in[2];
    const float* b1 = (const float*)d_in[3];
    const float* W2 = (const float*)d_in[4];
    const float* b2 = (const float*)d_in[5];
    const float* W3 = (const float*)d_in[6];
    const float* b3 = (const float*)d_in[7];
    float* out = (float*)d_out;
    const int N = in_sizes[0] / NFEAT;
    const int E = in_sizes[1] / 2;
    const int* src = ei;
    const int* dst = ei + E;
    const int NBK = (N + BNODES - 1) / BNODES;
    const int NBLK_E = (E + EPB - 1) / EPB;

    char* ws = (char*)d_ws;
    size_t off = 0;
    auto alloc = [&](size_t bytes) -> void* {
        void* p = ws + off;
        off += (bytes + 255) & ~(size_t)255;
        return p;
    };
    int*      bcnt    = (int*)alloc((size_t)NBK * 4);
    int*      ecnt    = (int*)alloc((size_t)NBK * NBLK_E * 4);
    uint_t*   bstore  = (uint_t*)alloc((size_t)NBK * BCAP * 4);
    uint_t*   colsort = (uint_t*)alloc((size_t)NBK * BCAP * 4);
    int*      rp      = (int*)alloc((size_t)NBK * (BNODES + 1) * 4);
    float*    dinv    = (float*)alloc((size_t)N * 4);
    uchar_t*  h8      = (uchar_t*)alloc((size_t)N * NHID);       // fp8 GEMM out [2][N][64]
    ushort_t* abuf    = (ushort_t*)alloc((size_t)N * NHID * 2);  // bf16 agg out [2][N][64]
    ushort_t* h3      = (ushort_t*)alloc((size_t)N * 64 * 2);    // padded [N][64] bf16
    ushort_t* Whi1    = (ushort_t*)alloc((size_t)NHID * NFEAT * 2);
    ushort_t* Whi2    = (ushort_t*)alloc((size_t)NHID * NHID * 2);
    ushort_t* Whi3    = (ushort_t*)alloc((size_t)64 * NHID * 2);
    (void)ws_size; (void)n_in; (void)out_size;

    // fused weight prep (T2/T3 k-permuted to match fp8 byte-pair order)
    int wtelems = NHID * NFEAT + NHID * NHID + 64 * NHID;
    k_wtall<<<(wtelems + 255) / 256, 256, 0, stream>>>(W1, W2, W3, Whi1, Whi2, Whi3);

    // edge partition (no global atomics; sorted coalesced writes) + bsort
    k_ehist<<<NBLK_E, 256, 0, stream>>>(dst, ecnt, E, NBK, NBLK_E);
    k_escan<<<NBK, 256, 0, stream>>>(ecnt, bcnt, NBLK_E);
    k_escatter<<<NBLK_E, 256, 0, stream>>>(src, dst, ecnt, bstore, E, NBK, NBLK_E);
    k_bsort<<<NBK, 256, 0, stream>>>(bstore, bcnt, colsort, rp, dinv, N);

    int ngemm = (N + 127) / 128;
    // layer 1
    k_gemm_mfma<NFEAT, true, 128, 0, 0><<<ngemm, 512, 0, stream>>>(x, Whi1, dinv, h8, N);
    k_agg_slice<<<NBK * 2, 256, 0, stream>>>(colsort, rp, h8, dinv, b1, abuf, N);
    // layer 2
    k_gemm_mfma<NHID, false, 128, 0, 0><<<ngemm, 512, 0, stream>>>(abuf, Whi2, dinv, h8, N);
    k_agg_slice<<<NBK * 2, 256, 0, stream>>>(colsort, rp, h8, dinv, b2, abuf, N);
    // layer 3 + log_softmax
    k_gemm_mfma<NHID, false, 64, 64, 1><<<ngemm, 512, 0, stream>>>(abuf, Whi3, dinv, h3, N);
    k_agg40_lsm<<<NBK, 256, 0, stream>>>(colsort, rp, h3, dinv, b3, out, N);
}

// Round 20
// 202.280 us; speedup vs baseline: 1.1847x; 1.0514x over previous
//
#include <hip/hip_runtime.h>
#include <math.h>

#define NFEAT 256
#define NHID 128
#define NCLASS 40
#define BNODES 128
#define BSHIFT 7
#define BCAP 2688
#define MAXBK 1024
#define EPB 8192

typedef unsigned short ushort_t;
typedef unsigned int uint_t;
typedef unsigned char uchar_t;
typedef __attribute__((ext_vector_type(8))) short bf16x8;
typedef __attribute__((ext_vector_type(4))) float f32x4;
typedef __attribute__((ext_vector_type(2))) float f32x2;

static __device__ inline float bf2f(ushort_t u) {
    union { uint_t u; float f; } v; v.u = (uint_t)u << 16; return v.f;
}
static __device__ inline ushort_t f2bf(float f) {
    uint_t u = __float_as_uint(f);
    u += 0x7FFF + ((u >> 16) & 1);           // round-to-nearest-even
    return (ushort_t)(u >> 16);
}
// async global->LDS 16B (dest = wave-uniform base + lane*16)
static __device__ __forceinline__ void gload16(const void* g, void* l) {
    __builtin_amdgcn_global_load_lds(
        (const __attribute__((address_space(1))) uint_t*)g,
        (__attribute__((address_space(3))) uint_t*)l, 16, 0, 0);
}
// fp8 e4m3 pack/unpack (gfx950 native)
static __device__ inline ushort_t pk2fp8(float a, float b) {
    return (ushort_t)__builtin_amdgcn_cvt_pk_fp8_f32(a, b, 0, false);
}
static __device__ inline f32x2 unpk_lo(uint_t w) {
    return __builtin_amdgcn_cvt_pk_f32_fp8(w, false);
}
static __device__ inline f32x2 unpk_hi(uint_t w) {
    return __builtin_amdgcn_cvt_pk_f32_fp8(w, true);
}

// ---------------- edge partition by dst-bucket: hist / scan / scatter --------

__global__ __launch_bounds__(256) void k_ehist(const int* __restrict__ dst,
                                               int* __restrict__ cnt,
                                               int E, int nbk, int nblk) {
    __shared__ int hist[MAXBK];
    int tid = threadIdx.x, be = blockIdx.x;
    for (int i = tid; i < nbk; i += 256) hist[i] = 0;
    __syncthreads();
    int e0 = be * EPB, e1 = min(e0 + EPB, E);
    for (int e = e0 + tid; e < e1; e += 256)
        atomicAdd(&hist[dst[e] >> BSHIFT], 1);          // LDS int atomic: native
    __syncthreads();
    for (int i = tid; i < nbk; i += 256)
        cnt[(size_t)i * nblk + be] = hist[i];
}

__global__ __launch_bounds__(256) void k_escan(int* __restrict__ cnt,
                                               int* __restrict__ bcnt, int nblk) {
    __shared__ int buf[256];
    int b = blockIdx.x, tid = threadIdx.x;
    int v = (tid < nblk) ? cnt[(size_t)b * nblk + tid] : 0;
    buf[tid] = v;
    __syncthreads();
    for (int off = 1; off < 256; off <<= 1) {
        int t = (tid >= off) ? buf[tid - off] : 0;
        __syncthreads();
        buf[tid] += t;
        __syncthreads();
    }
    if (tid < nblk) cnt[(size_t)b * nblk + tid] = buf[tid] - v;   // exclusive
    if (tid == 255) bcnt[b] = buf[255];                           // total
}

// block-local counting sort -> coalesced run writes
__global__ __launch_bounds__(256) void k_escatter(const int* __restrict__ src,
                                                  const int* __restrict__ dst,
                                                  const int* __restrict__ cnt,
                                                  uint_t* __restrict__ bstore,
                                                  int E, int nbk, int nblk) {
    __shared__ uint_t   sorted[EPB];     // 32 KB
    __shared__ ushort_t sortb[EPB];      // 16 KB
    __shared__ int hist[MAXBK];          // 4 KB
    __shared__ int lcur[MAXBK];          // 4 KB
    __shared__ int gadj[MAXBK];          // 4 KB
    __shared__ int buf[256];             // 1 KB
    int tid = threadIdx.x, be = blockIdx.x;
    for (int i = tid; i < MAXBK; i += 256) hist[i] = 0;
    __syncthreads();
    int e0 = be * EPB, e1 = min(e0 + EPB, E);
    for (int e = e0 + tid; e < e1; e += 256)
        atomicAdd(&hist[dst[e] >> BSHIFT], 1);
    __syncthreads();
    int base = tid * 4;
    int v0 = hist[base], v1 = hist[base + 1], v2 = hist[base + 2], v3 = hist[base + 3];
    int s = v0 + v1 + v2 + v3;
    buf[tid] = s;
    __syncthreads();
    for (int off = 1; off < 256; off <<= 1) {
        int t = (tid >= off) ? buf[tid - off] : 0;
        __syncthreads();
        buf[tid] += t;
        __syncthreads();
    }
    int run = buf[tid] - s;
    int ls0 = run, ls1 = run + v0, ls2 = run + v0 + v1, ls3 = run + v0 + v1 + v2;
    gadj[base]     = ((base     < nbk) ? cnt[(size_t)(base)     * nblk + be] : 0) - ls0;
    gadj[base + 1] = ((base + 1 < nbk) ? cnt[(size_t)(base + 1) * nblk + be] : 0) - ls1;
    gadj[base + 2] = ((base + 2 < nbk) ? cnt[(size_t)(base + 2) * nblk + be] : 0) - ls2;
    gadj[base + 3] = ((base + 3 < nbk) ? cnt[(size_t)(base + 3) * nblk + be] : 0) - ls3;
    lcur[base] = ls0; lcur[base + 1] = ls1; lcur[base + 2] = ls2; lcur[base + 3] = ls3;
    __syncthreads();
    for (int e = e0 + tid; e < e1; e += 256) {
        int d = dst[e];
        int b = d >> BSHIFT;
        uint_t rec = ((uint_t)(d & (BNODES - 1)) << 20) | (uint_t)src[e];
        int p = atomicAdd(&lcur[b], 1);              // LDS int atomic: native
        sorted[p] = rec;
        sortb[p] = (ushort_t)b;
    }
    __syncthreads();
    int cntL = e1 - e0;
    for (int i = tid; i < cntL; i += 256) {
        int bb = sortb[i];
        int idx = gadj[bb] + i;
        if (idx < BCAP)
            bstore[(size_t)bb * BCAP + idx] = sorted[i];
    }
}

// ---------------- per-bucket counting sort (LDS), + rp + dinv ----------------

__global__ __launch_bounds__(256) void k_bsort(const uint_t* __restrict__ bstore,
                                               const int* __restrict__ bcnt,
                                               uint_t* __restrict__ colsort,
                                               int* __restrict__ rp,
                                               float* __restrict__ dinv, int N) {
    __shared__ uint_t rec[BCAP];
    __shared__ uint_t srt[BCAP];
    __shared__ int hist[BNODES];
    __shared__ int scan[BNODES];
    __shared__ int cur[BNODES];
    int b = blockIdx.x, tid = threadIdx.x;
    if (tid < BNODES) hist[tid] = 0;
    __syncthreads();
    int cnt = min(bcnt[b], BCAP);
    const uint_t* gp = &bstore[(size_t)b * BCAP];
    for (int e = tid; e < cnt; e += 256) {
        uint_t r = gp[e];
        rec[e] = r;
        atomicAdd(&hist[r >> 20], 1);          // int LDS atomic: native
    }
    __syncthreads();
    if (tid < BNODES) scan[tid] = hist[tid];
    __syncthreads();
    for (int off = 1; off < BNODES; off <<= 1) {
        int v = 0;
        if (tid < BNODES && tid >= off) v = scan[tid - off];
        __syncthreads();
        if (tid < BNODES) scan[tid] += v;
        __syncthreads();
    }
    if (tid < BNODES) cur[tid] = scan[tid] - hist[tid];   // exclusive
    __syncthreads();
    for (int e = tid; e < cnt; e += 256) {
        uint_t r = rec[e];
        int p = atomicAdd(&cur[r >> 20], 1);   // int LDS atomic: native
        srt[p] = r & 0xFFFFF;
    }
    __syncthreads();
    uint_t* cs = &colsort[(size_t)b * BCAP];
    for (int e = tid; e < cnt; e += 256) cs[e] = srt[e];
    if (tid < BNODES) {
        rp[b * (BNODES + 1) + tid] = scan[tid] - hist[tid];
        int n = b * BNODES + tid;
        if (n < N) dinv[n] = rsqrtf((float)hist[tid] + 1.0f);
    }
    if (tid == 0) rp[b * (BNODES + 1) + BNODES] = cnt;
}

// ---------------- fused weight transpose -> bf16 -----------------------------
// T2,T3 rows permuted on k: phys kp -> logical k = (kp>>5)*32 + ((kp&1)<<4) + ((kp&31)>>1)

__global__ __launch_bounds__(256) void k_wtall(const float* __restrict__ W1,
                                               const float* __restrict__ W2,
                                               const float* __restrict__ W3,
                                               ushort_t* __restrict__ T1,
                                               ushort_t* __restrict__ T2,
                                               ushort_t* __restrict__ T3) {
    int idx = blockIdx.x * 256 + threadIdx.x;
    if (idx < NHID * NFEAT) {                                // T1[128][256] (no perm)
        int nrow = idx >> 8, k = idx & 255;
        T1[idx] = f2bf(W1[(size_t)k * NHID + nrow]);
    } else if ((idx -= NHID * NFEAT) < NHID * NHID) {        // T2[128][128] k-perm
        int nrow = idx >> 7, kp = idx & 127;
        int s = kp >> 5, pl = kp & 31;
        int k = s * 32 + ((pl & 1) << 4) + (pl >> 1);
        T2[idx] = f2bf(W2[(size_t)k * NHID + nrow]);
    } else if ((idx -= NHID * NHID) < 64 * NHID) {           // T3[64][128] k-perm, pad
        int nrow = idx >> 7, kp = idx & 127;
        int s = kp >> 5, pl = kp & 31;
        int k = s * 32 + ((pl & 1) << 4) + (pl >> 1);
        T3[idx] = f2bf(nrow < NCLASS ? W3[(size_t)k * NCLASS + nrow] : 0.f);
    }
}

// ---------------- MFMA GEMM (bf16 weights, BM=128, 512 thr / 8 waves) -------
// C = (A @ W) * dinv[row]   (pre-scaled h')
// MODE 0: out fp8 e4m3, slice-major [2][N][64] (64B rows), byte-pair packed
// MODE 2: out fp8 e4m3, row-major [N][64], LOGICAL col order (cols>=40 zero)
// A_FP32: A row-major fp32 (convert path); else A bf16 phys-order [2][N][64]

template<int K, bool A_FP32, int BN, int OST, int MODE>
__global__ __launch_bounds__(512) void k_gemm_mfma(const void* __restrict__ Ap,
                                                   const ushort_t* __restrict__ Whi,
                                                   const float* __restrict__ dinv,
                                                   void* __restrict__ Cv, int n) {
    const int BM = 128, BK = 64;
    __shared__ ushort_t As[BM * BK];
    __shared__ ushort_t Bh[BN * BK];
    const int tid = threadIdx.x;
    const int w = tid >> 6, l = tid & 63;
    const int row0 = blockIdx.x * BM;
    const int NJ = BN / 16;
    f32x4 acc[NJ] = {};

    for (int k0 = 0; k0 < K; k0 += BK) {
        // ---- stage A tile (128 x 64) ----
        if (A_FP32) {
            int r = tid >> 2;                       // 0..127
            if (row0 + r < n) {
                const float* A = (const float*)Ap;
                const float* ap = &A[(size_t)(row0 + r) * K + k0];
#pragma unroll
                for (int h = 0; h < 2; h++) {
                    int q = (tid & 3) * 2 + h;
                    float4 v0 = *(const float4*)&ap[q * 8];
                    float4 v1 = *(const float4*)&ap[q * 8 + 4];
                    ushort4 o0, o1;
                    o0.x = f2bf(v0.x); o0.y = f2bf(v0.y); o0.z = f2bf(v0.z); o0.w = f2bf(v0.w);
                    o1.x = f2bf(v1.x); o1.y = f2bf(v1.y); o1.z = f2bf(v1.z); o1.w = f2bf(v1.w);
                    int pc = q ^ (r & 7);
                    *(ushort4*)&As[r * 64 + pc * 8]     = o0;
                    *(ushort4*)&As[r * 64 + pc * 8 + 4] = o1;
                }
            }
        } else {
            const ushort_t* A = (const ushort_t*)Ap;
#pragma unroll
            for (int m = 0; m < 2; m++) {           // 1024 chunks, 2 rounds of 512
                int unit = m * 512 + tid;
                int r = unit >> 3, pc = unit & 7;
                int lc = pc ^ (r & 7);
                int kk = k0 + lc * 8;
                size_t rowg = (size_t)min(row0 + r, n - 1);   // clamp: junk rows unused
                const ushort_t* srcp = &A[(size_t)(kk >> 6) * n * 64 + rowg * 64 + (kk & 63)];
                gload16(srcp, &As[(size_t)unit * 8]);
            }
        }
        // ---- stage B tile (BN x 64): BN*8 chunks, BN/64 rounds of 512 ----
#pragma unroll
        for (int m = 0; m < BN / 64; m++) {
            int unit = m * 512 + tid;
            int r = unit >> 3, pc = unit & 7;
            int lc = pc ^ (r & 7);
            gload16(&Whi[(size_t)r * K + k0 + lc * 8], &Bh[(size_t)unit * 8]);
        }
        __syncthreads();   // drains vmcnt + lgkmcnt

        const int lo4 = l & 15;
        const int swz = l & 7;
#pragma unroll
        for (int kh = 0; kh < BK; kh += 32) {
            int q = (kh >> 3) + (l >> 4);
            int ra = w * 16 + lo4;
            bf16x8 a = *(const bf16x8*)&As[ra * 64 + (q ^ swz) * 8];
#pragma unroll
            for (int j = 0; j < NJ; j++) {
                int rb = j * 16 + lo4;
                bf16x8 bh = *(const bf16x8*)&Bh[rb * 64 + (q ^ swz) * 8];
                acc[j] = __builtin_amdgcn_mfma_f32_16x16x32_bf16(a, bh, acc[j], 0, 0, 0);
            }
        }
        __syncthreads();
    }

    float dnv[4];
#pragma unroll
    for (int r = 0; r < 4; r++) {
        int row = row0 + w * 16 + (l >> 4) * 4 + r;
        dnv[r] = (row < n) ? dinv[row] : 0.f;
    }
    const int cb = l & 15;
    if (MODE == 0) {
        // fp8 pack: old slice s = 2t+sub -> row t, bytes sub*32 + {2cb, 2cb+1}
        uchar_t* C8 = (uchar_t*)Cv;
#pragma unroll
        for (int s = 0; s < NJ / 2; s++) {
            int t = s >> 1, sub = s & 1;
#pragma unroll
            for (int r = 0; r < 4; r++) {
                int row = row0 + w * 16 + (l >> 4) * 4 + r;
                if (row < n) {
                    ushort_t pk = pk2fp8(dnv[r] * acc[2 * s][r], dnv[r] * acc[2 * s + 1][r]);
                    *(ushort_t*)&C8[(size_t)t * n * 64 + (size_t)row * 64 + sub * 32 + cb * 2] = pk;
                }
            }
        }
    } else {
        // MODE 2: fp8 logical order [N][64]
        uchar_t* C8 = (uchar_t*)Cv;
#pragma unroll
        for (int j = 0; j < NJ; j++) {
#pragma unroll
            for (int r = 0; r < 4; r++) {
                int row = row0 + w * 16 + (l >> 4) * 4 + r;
                if (row < n)
                    C8[(size_t)row * OST + j * 16 + cb] =
                        (uchar_t)pk2fp8(dnv[r] * acc[j][r], 0.f);
            }
        }
    }
}

// ---------------- sliced aggregation (layers 1,2) — fp8 64B line rows -------
// block=(bucket,slice); slice=blk&1; h8 [2][N][64] fp8 (phys byte order)
// 4 lanes/node x uint4 = full 64B line; out bf16 [2][N][64] same phys order

__global__ __launch_bounds__(256) void k_agg_slice(const uint_t* __restrict__ colsort,
                                                   const int* __restrict__ rp,
                                                   const uchar_t* __restrict__ h8,
                                                   const float* __restrict__ dinv,
                                                   const float* __restrict__ bias,
                                                   ushort_t* __restrict__ out, int N) {
    __shared__ int srp[BNODES + 1];
    __shared__ uint_t cols[BCAP];
    int blk = blockIdx.x;
    int slice = blk & 1, b = blk >> 1;
    int tid = threadIdx.x;
    if (tid <= BNODES) srp[tid] = rp[b * (BNODES + 1) + tid];
    __syncthreads();
    int cnt = srp[BNODES];
    for (int e = tid; e < cnt; e += 256) cols[e] = colsort[(size_t)b * BCAP + e];
    __syncthreads();
    int fq = tid & 3;                  // 16B quarter of the 64B row (16 fp8 feats)
    int q  = tid >> 2;                 // node slot 0..63
    const uchar_t* hs = &h8[(size_t)slice * N * 64 + fq * 16];
    float bv[16];
#pragma unroll
    for (int i = 0; i < 16; i++) {
        int p = fq * 16 + i;
        int s = 2 * slice + (p >> 5), pl = p & 31;
        bv[i] = bias[s * 32 + ((pl & 1) << 4) + (pl >> 1)];
    }
    for (int nl = q; nl < BNODES; nl += 64) {
        int n = b * BNODES + nl;
        if (n >= N) break;
        int e = srp[nl], e1 = srp[nl + 1];
        f32x2 a2[8];
        {
            uint4 sv = *(const uint4*)&hs[(size_t)n * 64];
            a2[0] = unpk_lo(sv.x); a2[1] = unpk_hi(sv.x);
            a2[2] = unpk_lo(sv.y); a2[3] = unpk_hi(sv.y);
            a2[4] = unpk_lo(sv.z); a2[5] = unpk_hi(sv.z);
            a2[6] = unpk_lo(sv.w); a2[7] = unpk_hi(sv.w);
        }
        for (; e + 4 <= e1; e += 4) {
            uint4 v[4];
#pragma unroll
            for (int i = 0; i < 4; i++) v[i] = *(const uint4*)&hs[(size_t)cols[e + i] * 64];
#pragma unroll
            for (int i = 0; i < 4; i++) {
                a2[0] += unpk_lo(v[i].x); a2[1] += unpk_hi(v[i].x);
                a2[2] += unpk_lo(v[i].y); a2[3] += unpk_hi(v[i].y);
                a2[4] += unpk_lo(v[i].z); a2[5] += unpk_hi(v[i].z);
                a2[6] += unpk_lo(v[i].w); a2[7] += unpk_hi(v[i].w);
            }
        }
        for (; e < e1; e++) {
            uint4 v = *(const uint4*)&hs[(size_t)cols[e] * 64];
            a2[0] += unpk_lo(v.x); a2[1] += unpk_hi(v.x);
            a2[2] += unpk_lo(v.y); a2[3] += unpk_hi(v.y);
            a2[4] += unpk_lo(v.z); a2[5] += unpk_hi(v.z);
            a2[6] += unpk_lo(v.w); a2[7] += unpk_hi(v.w);
        }
        float dn = dinv[n];
        uint_t o[8];
#pragma unroll
        for (int k = 0; k < 8; k++) {
            float r0 = fmaxf(fmaf(dn, a2[k].x, bv[2 * k]),     0.f);
            float r1 = fmaxf(fmaf(dn, a2[k].y, bv[2 * k + 1]), 0.f);
            o[k] = ((uint_t)f2bf(r1) << 16) | f2bf(r0);
        }
        ushort_t* op = &out[((size_t)slice * N + n) * 64 + fq * 16];
        *(uint4*)&op[0] = make_uint4(o[0], o[1], o[2], o[3]);
        *(uint4*)&op[8] = make_uint4(o[4], o[5], o[6], o[7]);
    }
}

// ---------------- layer-3 aggregation + log_softmax — fp8 64B rows ----------
// h3 [N][64] fp8, LOGICAL order (cols>=40 are zero); 4 lanes/node x uint4

__global__ __launch_bounds__(256) void k_agg40_lsm(const uint_t* __restrict__ colsort,
                                                   const int* __restrict__ rp,
                                                   const uchar_t* __restrict__ h3,
                                                   const float* __restrict__ dinv,
                                                   const float* __restrict__ bias,
                                                   float* __restrict__ out, int N) {
    __shared__ int srp[BNODES + 1];
    __shared__ uint_t cols[BCAP];
    int b = blockIdx.x, tid = threadIdx.x;
    if (tid <= BNODES) srp[tid] = rp[b * (BNODES + 1) + tid];
    __syncthreads();
    int cnt = srp[BNODES];
    for (int e = tid; e < cnt; e += 256) cols[e] = colsort[(size_t)b * BCAP + e];
    __syncthreads();
    int fq = tid & 3;                  // 16B quarter (16 logical cols)
    int q  = tid >> 2;                 // node slot 0..63
    const uchar_t* hs = &h3[fq * 16];
    float bv[16];
#pragma unroll
    for (int i = 0; i < 16; i++) {
        int c = fq * 16 + i;
        bv[i] = (c < NCLASS) ? bias[c] : 0.f;
    }
    for (int nl = q; nl < BNODES; nl += 64) {
        int n = b * BNODES + nl;
        if (n >= N) break;
        int e = srp[nl], e1 = srp[nl + 1];
        f32x2 a2[8];
        {
            uint4 sv = *(const uint4*)&hs[(size_t)n * 64];
            a2[0] = unpk_lo(sv.x); a2[1] = unpk_hi(sv.x);
            a2[2] = unpk_lo(sv.y); a2[3] = unpk_hi(sv.y);
            a2[4] = unpk_lo(sv.z); a2[5] = unpk_hi(sv.z);
            a2[6] = unpk_lo(sv.w); a2[7] = unpk_hi(sv.w);
        }
        for (; e + 4 <= e1; e += 4) {
            uint4 v[4];
#pragma unroll
            for (int i = 0; i < 4; i++) v[i] = *(const uint4*)&hs[(size_t)cols[e + i] * 64];
#pragma unroll
            for (int i = 0; i < 4; i++) {
                a2[0] += unpk_lo(v[i].x); a2[1] += unpk_hi(v[i].x);
                a2[2] += unpk_lo(v[i].y); a2[3] += unpk_hi(v[i].y);
                a2[4] += unpk_lo(v[i].z); a2[5] += unpk_hi(v[i].z);
                a2[6] += unpk_lo(v[i].w); a2[7] += unpk_hi(v[i].w);
            }
        }
        for (; e < e1; e++) {
            uint4 v = *(const uint4*)&hs[(size_t)cols[e] * 64];
            a2[0] += unpk_lo(v.x); a2[1] += unpk_hi(v.x);
            a2[2] += unpk_lo(v.y); a2[3] += unpk_hi(v.y);
            a2[4] += unpk_lo(v.z); a2[5] += unpk_hi(v.z);
            a2[6] += unpk_lo(v.w); a2[7] += unpk_hi(v.w);
        }
        float dn = dinv[n];
        float z[16];
        float m = -INFINITY;
#pragma unroll
        for (int k = 0; k < 8; k++) {
            int c0 = fq * 16 + 2 * k;
            z[2 * k]     = (c0     < NCLASS) ? fmaf(dn, a2[k].x, bv[2 * k])     : -INFINITY;
            z[2 * k + 1] = (c0 + 1 < NCLASS) ? fmaf(dn, a2[k].y, bv[2 * k + 1]) : -INFINITY;
            m = fmaxf(m, fmaxf(z[2 * k], z[2 * k + 1]));
        }
#pragma unroll
        for (int off = 1; off < 4; off <<= 1) m = fmaxf(m, __shfl_xor(m, off, 4));
        float p = 0.f;
#pragma unroll
        for (int i = 0; i < 16; i++)
            if (fq * 16 + i < NCLASS) p += expf(z[i] - m);
#pragma unroll
        for (int off = 1; off < 4; off <<= 1) p += __shfl_xor(p, off, 4);
        float lse = m + logf(p);
        float* op = &out[(size_t)n * NCLASS];
        if (fq < 2) {
#pragma unroll
            for (int h = 0; h < 4; h++) {
                float4 o = make_float4(z[h * 4] - lse, z[h * 4 + 1] - lse,
                                       z[h * 4 + 2] - lse, z[h * 4 + 3] - lse);
                *(float4*)&op[fq * 16 + h * 4] = o;
            }
        } else if (fq == 2) {
#pragma unroll
            for (int h = 0; h < 2; h++) {
                float4 o = make_float4(z[h * 4] - lse, z[h * 4 + 1] - lse,
                                       z[h * 4 + 2] - lse, z[h * 4 + 3] - lse);
                *(float4*)&op[32 + h * 4] = o;
            }
        }
    }
}

// ---------------- launch ----------------

extern "C" void kernel_launch(void* const* d_in, const int* in_sizes, int n_in,
                              void* d_out, int out_size, void* d_ws, size_t ws_size,
                              hipStream_t stream) {
    const float* x  = (const float*)d_in[0];
    const int*   ei = (const int*)d_in[1];
    const float* W1 = (const float*)d_in[2];
    const float* b1 = (const float*)d_in[3];
    const float* W2 = (const float*)d_in[4];
    const float* b2 = (const float*)d_in[5];
    const float* W3 = (const float*)d_in[6];
    const float* b3 = (const float*)d_in[7];
    float* out = (float*)d_out;
    const int N = in_sizes[0] / NFEAT;
    const int E = in_sizes[1] / 2;
    const int* src = ei;
    const int* dst = ei + E;
    const int NBK = (N + BNODES - 1) / BNODES;
    const int NBLK_E = (E + EPB - 1) / EPB;

    char* ws = (char*)d_ws;
    size_t off = 0;
    auto alloc = [&](size_t bytes) -> void* {
        void* p = ws + off;
        off += (bytes + 255) & ~(size_t)255;
        return p;
    };
    int*      bcnt    = (int*)alloc((size_t)NBK * 4);
    int*      ecnt    = (int*)alloc((size_t)NBK * NBLK_E * 4);
    uint_t*   bstore  = (uint_t*)alloc((size_t)NBK * BCAP * 4);
    uint_t*   colsort = (uint_t*)alloc((size_t)NBK * BCAP * 4);
    int*      rp      = (int*)alloc((size_t)NBK * (BNODES + 1) * 4);
    float*    dinv    = (float*)alloc((size_t)N * 4);
    uchar_t*  h8      = (uchar_t*)alloc((size_t)N * NHID);       // fp8 GEMM out [2][N][64]
    ushort_t* abuf    = (ushort_t*)alloc((size_t)N * NHID * 2);  // bf16 agg out [2][N][64]
    uchar_t*  h38     = (uchar_t*)alloc((size_t)N * 64);         // fp8 GEMM3 out [N][64]
    ushort_t* Whi1    = (ushort_t*)alloc((size_t)NHID * NFEAT * 2);
    ushort_t* Whi2    = (ushort_t*)alloc((size_t)NHID * NHID * 2);
    ushort_t* Whi3    = (ushort_t*)alloc((size_t)64 * NHID * 2);
    (void)ws_size; (void)n_in; (void)out_size;

    // fused weight prep (T2/T3 k-permuted to match fp8 byte-pair order)
    int wtelems = NHID * NFEAT + NHID * NHID + 64 * NHID;
    k_wtall<<<(wtelems + 255) / 256, 256, 0, stream>>>(W1, W2, W3, Whi1, Whi2, Whi3);

    // edge partition (no global atomics; sorted coalesced writes) + bsort
    k_ehist<<<NBLK_E, 256, 0, stream>>>(dst, ecnt, E, NBK, NBLK_E);
    k_escan<<<NBK, 256, 0, stream>>>(ecnt, bcnt, NBLK_E);
    k_escatter<<<NBLK_E, 256, 0, stream>>>(src, dst, ecnt, bstore, E, NBK, NBLK_E);
    k_bsort<<<NBK, 256, 0, stream>>>(bstore, bcnt, colsort, rp, dinv, N);

    int ngemm = (N + 127) / 128;
    // layer 1
    k_gemm_mfma<NFEAT, true, 128, 0, 0><<<ngemm, 512, 0, stream>>>(x, Whi1, dinv, h8, N);
    k_agg_slice<<<NBK * 2, 256, 0, stream>>>(colsort, rp, h8, dinv, b1, abuf, N);
    // layer 2
    k_gemm_mfma<NHID, false, 128, 0, 0><<<ngemm, 512, 0, stream>>>(abuf, Whi2, dinv, h8, N);
    k_agg_slice<<<NBK * 2, 256, 0, stream>>>(colsort, rp, h8, dinv, b2, abuf, N);
    // layer 3 + log_softmax (fp8 logical h3)
    k_gemm_mfma<NHID, false, 64, 64, 2><<<ngemm, 512, 0, stream>>>(abuf, Whi3, dinv, h38, N);
    k_agg40_lsm<<<NBK, 256, 0, stream>>>(colsort, rp, h38, dinv, b3, out, N);
}